// Round 20
// baseline (203.369 us; speedup 1.0000x reference)
//
#include <hip/hip_runtime.h>

#define NORIENT 8

// XCD-aware block swizzle (bijective when gridDim % 8 == 0; all our grids are).
__device__ __forceinline__ unsigned xcd_swz(unsigned bid, unsigned nwg) {
    unsigned chunk = nwg >> 3;
    return (nwg & 7u) ? bid : (bid & 7u) * chunk + (bid >> 3);
}

// -------- forward, wave-per-channel: stride-2 5x5 conv, 1 -> 8 ch --------
// (exact R19 version)
__global__ void fwd_conv_wave_kernel(const float* __restrict__ in, long in_img_stride,
                                     const float* __restrict__ filt,
                                     float* __restrict__ out,
                                     int H, int W, int OH, int OW, int N) {
    constexpr int SROW = 104;
    __shared__ float tile[67 * SROW];      // 27,872 B

    int nbx = OW >> 5, nby = OH >> 5;
    unsigned sb = xcd_swz(blockIdx.x, gridDim.x);
    int bx = (int)(sb % nbx);
    unsigned t = sb / nbx;
    int by = (int)(t % nby);
    int n = (int)(t / nby);

    const float* __restrict__ ip = in + (long)n * in_img_stride;
    int tid = threadIdx.x;

    int w = __builtin_amdgcn_readfirstlane(tid >> 6);
    const float* __restrict__ F = filt + w * 25;
    float Wt[25];
#pragma unroll
    for (int k = 0; k < 25; ++k) Wt[k] = F[k];

    int gy0 = 64 * by - 2, gx0 = 64 * bx - 4;
#pragma unroll
    for (int k = 0; k < 3; ++k) {
        int e = tid + k * 512;
        if (e < 67 * 18) {
            int row = e / 18, m = e - row * 18;
            int gy = gy0 + row, gx = gx0 + 4 * m;
            bool vl = (gy >= 0) & (gy < H) & (gx >= 0) & (gx <= W - 4);
            float4 val = *(const float4*)(ip + (vl ? ((long)gy * W + gx) : 0));
            float msk = vl ? 1.f : 0.f;
            int off = row * SROW + 4 * m + 4 * (m >> 1);
            *(float4*)&tile[off] = make_float4(val.x * msk, val.y * msk,
                                               val.z * msk, val.w * msk);
        }
    }
    __syncthreads();

    int lane = tid & 63;
    int lx = lane & 7, ly = lane >> 3;

    float acc[4][4];
#pragma unroll
    for (int o = 0; o < 4; ++o)
#pragma unroll
        for (int dx = 0; dx < 4; ++dx) acc[o][dx] = 0.f;

#pragma unroll
    for (int r = 0; r < 11; ++r) {
        int base = (8 * ly + r) * SROW + 12 * lx;
        float2 A2 = *(const float2*)&tile[base + 2];
        float4 B  = *(const float4*)&tile[base + 4];
        float4 C  = *(const float4*)&tile[base + 12];
        float  D  = tile[base + 16];
        float Q[11] = {A2.x, A2.y, B.x, B.y, B.z, B.w, C.x, C.y, C.z, C.w, D};

#pragma unroll
        for (int o = 0; o < 4; ++o) {
            int i = r - 2 * o;
            if (i < 0 || i > 4) continue;
#pragma unroll
            for (int j = 0; j < 5; ++j) {
                float wv = Wt[i * 5 + j];
#pragma unroll
                for (int dx = 0; dx < 4; ++dx)
                    acc[o][dx] = fmaf(Q[2 * dx + j], wv, acc[o][dx]);
            }
        }
    }

    long cs = (long)OH * OW;
    int oy = 32 * by + 4 * ly, ox = 32 * bx + 4 * lx;
    long ob = ((long)n * NORIENT + w) * cs + (long)oy * OW + ox;
#pragma unroll
    for (int o = 0; o < 4; ++o)
        *(float4*)(out + ob + (long)o * OW) =
            make_float4(acc[o][0], acc[o][1], acc[o][2], acc[o][3]);
}

// -------- fused fwd level 4 + inv level 1: one block = one image (R18) --------
__global__ void fwd4_inv1_fused_kernel(const float* __restrict__ l2, // [n][8][64][64]
                                       const float* __restrict__ fwd_f,
                                       const float* __restrict__ inv_f,
                                       float* __restrict__ r1) {     // [n][64][64]
    constexpr int SROW = 104;
    __shared__ float tile[67 * SROW];        // 27,872 B
    __shared__ float l1t[NORIENT * 32 * 32]; // 32,768 B

    int n = blockIdx.x;
    const float* __restrict__ ip = l2 + (long)n * 8 * 64 * 64;   // channel 0 plane
    int tid = threadIdx.x;

    int w = __builtin_amdgcn_readfirstlane(tid >> 6);
    {
        const float* __restrict__ F = fwd_f + w * 25;
        float Wt[25];
#pragma unroll
        for (int k = 0; k < 25; ++k) Wt[k] = F[k];

#pragma unroll
        for (int k = 0; k < 3; ++k) {
            int e = tid + k * 512;
            if (e < 67 * 18) {
                int row = e / 18, m = e - row * 18;
                int gy = -2 + row, gx = -4 + 4 * m;
                bool vl = (gy >= 0) & (gy < 64) & (gx >= 0) & (gx <= 60);
                float4 val = *(const float4*)(ip + (vl ? ((long)gy * 64 + gx) : 0));
                float msk = vl ? 1.f : 0.f;
                int off = row * SROW + 4 * m + 4 * (m >> 1);
                *(float4*)&tile[off] = make_float4(val.x * msk, val.y * msk,
                                                   val.z * msk, val.w * msk);
            }
        }
        __syncthreads();

        int lane = tid & 63;
        int lx = lane & 7, ly = lane >> 3;

        float acc[4][4];
#pragma unroll
        for (int o = 0; o < 4; ++o)
#pragma unroll
            for (int dx = 0; dx < 4; ++dx) acc[o][dx] = 0.f;

#pragma unroll
        for (int r = 0; r < 11; ++r) {
            int base = (8 * ly + r) * SROW + 12 * lx;
            float2 A2 = *(const float2*)&tile[base + 2];
            float4 B  = *(const float4*)&tile[base + 4];
            float4 C  = *(const float4*)&tile[base + 12];
            float  D  = tile[base + 16];
            float Q[11] = {A2.x, A2.y, B.x, B.y, B.z, B.w, C.x, C.y, C.z, C.w, D};

#pragma unroll
            for (int o = 0; o < 4; ++o) {
                int i = r - 2 * o;
                if (i < 0 || i > 4) continue;
#pragma unroll
                for (int j = 0; j < 5; ++j) {
                    float wv = Wt[i * 5 + j];
#pragma unroll
                    for (int dx = 0; dx < 4; ++dx)
                        acc[o][dx] = fmaf(Q[2 * dx + j], wv, acc[o][dx]);
                }
            }
        }

#pragma unroll
        for (int o = 0; o < 4; ++o)
            *(float4*)&l1t[w * 1024 + (4 * ly + o) * 32 + 4 * lx] =
                make_float4(acc[o][0], acc[o][1], acc[o][2], acc[o][3]);
    }
    __syncthreads();

    if (tid < 256) {
        int b0 = tid & 15, a0 = tid >> 4;

        bool fmv = a0 > 0, fpv = a0 < 15;
        bool um = b0 > 0, up = b0 < 15;
        float fm = fmv ? 1.f : 0.f, fp_ = fpv ? 1.f : 0.f;
        int r0 = (fmv ? 2 * a0 - 1 : 0) * 32;
        int r1o = (2 * a0) * 32;
        int r2o = (2 * a0 + 1) * 32;
        int r3o = (fpv ? 2 * a0 + 2 : 2 * a0 + 1) * 32;
        int cL = um ? 2 * b0 - 2 : 0;
        int cM = 2 * b0;
        int cR = up ? 2 * b0 + 2 : 0;
        const int ro[4] = {r0, r1o, r2o, r3o};
        const float rm[4] = {fm, 1.f, 1.f, fp_};

        float acc[2][2][2][2];
#pragma unroll
        for (int i = 0; i < 2; ++i)
#pragma unroll
            for (int j = 0; j < 2; ++j)
#pragma unroll
                for (int k = 0; k < 2; ++k)
#pragma unroll
                    for (int l = 0; l < 2; ++l) acc[i][j][k][l] = 0.f;

#pragma unroll
        for (int c = 0; c < NORIENT; ++c) {
            const float* __restrict__ F = inv_f + c * 25;
            int coff = c * 1024;
            float P[4][4];
#pragma unroll
            for (int r = 0; r < 4; ++r) {
                int base = coff + ro[r];
                float2 L = *(const float2*)&l1t[base + cL];
                float2 M = *(const float2*)&l1t[base + cM];
                float2 R = *(const float2*)&l1t[base + cR];
                float mask = rm[r];
                P[r][0] = (um ? L.y : 0.f) * mask;
                P[r][1] = M.x * mask;
                P[r][2] = M.y * mask;
                P[r][3] = (up ? R.x : 0.f) * mask;
            }
#pragma unroll
            for (int a = 0; a < 3; ++a) {
#pragma unroll
                for (int b = 0; b < 3; ++b) {
                    float w00 = F[(4 - 2 * a) * 5 + (4 - 2 * b)];
                    float w01 = (b >= 1) ? F[(4 - 2 * a) * 5 + (5 - 2 * b)] : 0.f;
                    float w10 = (a >= 1) ? F[(5 - 2 * a) * 5 + (4 - 2 * b)] : 0.f;
                    float w11 = (a >= 1 && b >= 1) ? F[(5 - 2 * a) * 5 + (5 - 2 * b)] : 0.f;
#pragma unroll
                    for (int sr = 0; sr < 2; ++sr) {
#pragma unroll
                        for (int sc = 0; sc < 2; ++sc) {
                            float pv = P[sr + a][sc + b];
                            acc[sr][sc][0][0] = fmaf(pv, w00, acc[sr][sc][0][0]);
                            if (b >= 1) acc[sr][sc][0][1] = fmaf(pv, w01, acc[sr][sc][0][1]);
                            if (a >= 1) acc[sr][sc][1][0] = fmaf(pv, w10, acc[sr][sc][1][0]);
                            if (a >= 1 && b >= 1)
                                        acc[sr][sc][1][1] = fmaf(pv, w11, acc[sr][sc][1][1]);
                        }
                    }
                }
            }
        }

        long ob = (long)n * 4096 + (long)(4 * a0) * 64 + 4 * b0;
        *(float4*)(r1 + ob)       = make_float4(acc[0][0][0][0], acc[0][0][0][1],
                                                acc[0][1][0][0], acc[0][1][0][1]);
        *(float4*)(r1 + ob + 64)  = make_float4(acc[0][0][1][0], acc[0][0][1][1],
                                                acc[0][1][1][0], acc[0][1][1][1]);
        *(float4*)(r1 + ob + 128) = make_float4(acc[1][0][0][0], acc[1][0][0][1],
                                                acc[1][1][0][0], acc[1][1][0][1]);
        *(float4*)(r1 + ob + 192) = make_float4(acc[1][0][1][0], acc[1][0][1][1],
                                                acc[1][1][1][0], acc[1][1][1][1]);
    }
}

// -------- inverse direct, R20: explicit 2-deep channel pipeline --------
// R19 merged loads (8 VMEM/channel) + R20 change: channel c+1's loads issue
// BEFORE channel c's FMA block via named cur/next register pairs (ca/cb,
// na/nb), rotated per iteration (full unroll -> register renaming, rule #20).
// Masks/edge-selects applied at compute time so the next-channel loads stay
// independent of current-channel FMAs. FMA set identical to R4-verified code.
__global__ void inv_tconv_kernel(const float* __restrict__ rec, long rec_img_stride,
                                 const float* __restrict__ coef,
                                 const float* __restrict__ filt,
                                 float* __restrict__ out,
                                 int h, int w, int N) {
    int h2 = h >> 1, w2 = w >> 1;
    unsigned sb = xcd_swz(blockIdx.x, gridDim.x);
    long idx = (long)sb * blockDim.x + threadIdx.x;
    long total = (long)N * h2 * w2;
    if (idx >= total) return;
    int b0 = (int)(idx % w2);
    long t = idx / w2;
    int a0 = (int)(t % h2);
    int n = (int)(t / h2);

    const float* __restrict__ rp = rec + (long)n * rec_img_stride;
    const float* __restrict__ cp = coef + (long)n * (long)NORIENT * h * w;
    long cs = (long)h * w;

    bool fmv = a0 > 0, fpv = a0 < h2 - 1;
    bool um = b0 > 0, up = b0 < w2 - 1;
    float fm = fmv ? 1.f : 0.f, fp_ = fpv ? 1.f : 0.f;
    int r0 = (fmv ? 2 * a0 - 1 : 0) * w;
    int r1 = (2 * a0) * w;
    int r2 = (2 * a0 + 1) * w;
    int r3 = (fpv ? 2 * a0 + 2 : 2 * a0 + 1) * w;
    int am  = um ? 2 * b0 - 1 : 0;
    int bm2 = up ? 2 * b0 + 1 : w - 2;
    const int ro[4] = {r0, r1, r2, r3};
    const float rm[4] = {fm, 1.f, 1.f, fp_};

    float acc[2][2][2][2];  // [sr][sc][dy][dx]
#pragma unroll
    for (int i = 0; i < 2; ++i)
#pragma unroll
        for (int j = 0; j < 2; ++j)
#pragma unroll
            for (int k = 0; k < 2; ++k)
#pragma unroll
                for (int l = 0; l < 2; ++l) acc[i][j][k][l] = 0.f;

    float2 ca[4], cb[4];     // current channel's raw loads
#pragma unroll
    for (int r = 0; r < 4; ++r) {
        ca[r] = *(const float2*)(rp + ro[r] + am);
        cb[r] = *(const float2*)(rp + ro[r] + bm2);
    }

#pragma unroll
    for (int c = 0; c < NORIENT; ++c) {
        float2 na[4], nb[4];
        if (c < NORIENT - 1) {           // issue next channel's loads FIRST
            const float* __restrict__ src = cp + (long)(c + 1) * cs;
#pragma unroll
            for (int r = 0; r < 4; ++r) {
                na[r] = *(const float2*)(src + ro[r] + am);
                nb[r] = *(const float2*)(src + ro[r] + bm2);
            }
        }

        const float* __restrict__ F = filt + c * 25;
        float P[4][4];
#pragma unroll
        for (int r = 0; r < 4; ++r) {
            float mask = rm[r];
            P[r][0] = (um ? ca[r].x : 0.f) * mask;
            P[r][1] = (um ? ca[r].y : ca[r].x) * mask;
            P[r][2] = (up ? cb[r].x : cb[r].y) * mask;
            P[r][3] = (up ? cb[r].y : 0.f) * mask;
        }
#pragma unroll
        for (int a = 0; a < 3; ++a) {
#pragma unroll
            for (int b = 0; b < 3; ++b) {
                float w00 = F[(4 - 2 * a) * 5 + (4 - 2 * b)];
                float w01 = (b >= 1) ? F[(4 - 2 * a) * 5 + (5 - 2 * b)] : 0.f;
                float w10 = (a >= 1) ? F[(5 - 2 * a) * 5 + (4 - 2 * b)] : 0.f;
                float w11 = (a >= 1 && b >= 1) ? F[(5 - 2 * a) * 5 + (5 - 2 * b)] : 0.f;
#pragma unroll
                for (int sr = 0; sr < 2; ++sr) {
#pragma unroll
                    for (int sc = 0; sc < 2; ++sc) {
                        float pv = P[sr + a][sc + b];
                        acc[sr][sc][0][0] = fmaf(pv, w00, acc[sr][sc][0][0]);
                        if (b >= 1) acc[sr][sc][0][1] = fmaf(pv, w01, acc[sr][sc][0][1]);
                        if (a >= 1) acc[sr][sc][1][0] = fmaf(pv, w10, acc[sr][sc][1][0]);
                        if (a >= 1 && b >= 1)
                                    acc[sr][sc][1][1] = fmaf(pv, w11, acc[sr][sc][1][1]);
                    }
                }
            }
        }

        if (c < NORIENT - 1) {
#pragma unroll
            for (int r = 0; r < 4; ++r) { ca[r] = na[r]; cb[r] = nb[r]; }
        }
    }

    int OW = w << 1;
    long ob = (long)n * 4 * cs + (long)(4 * a0) * OW + 4 * b0;
    *(float4*)(out + ob)          = make_float4(acc[0][0][0][0], acc[0][0][0][1],
                                                acc[0][1][0][0], acc[0][1][0][1]);
    *(float4*)(out + ob + OW)     = make_float4(acc[0][0][1][0], acc[0][0][1][1],
                                                acc[0][1][1][0], acc[0][1][1][1]);
    *(float4*)(out + ob + 2 * OW) = make_float4(acc[1][0][0][0], acc[1][0][0][1],
                                                acc[1][1][0][0], acc[1][1][0][1]);
    *(float4*)(out + ob + 3 * OW) = make_float4(acc[1][0][1][0], acc[1][0][1][1],
                                                acc[1][1][1][0], acc[1][1][1][1]);
}

extern "C" void kernel_launch(void* const* d_in, const int* in_sizes, int n_in,
                              void* d_out, int out_size, void* d_ws, size_t ws_size,
                              hipStream_t stream) {
    const float* x     = (const float*)d_in[0];
    const float* fwd_f = (const float*)d_in[1];
    const float* inv_f = (const float*)d_in[2];
    float* out = (float*)d_out;
    float* ws  = (float*)d_ws;

    const int N = 32;

    // workspace layout (floats) — all offsets multiples of 4 -> 16B aligned
    float* l4 = ws;                  // 32*8*256*256 = 16,777,216
    float* l3 = l4 + 16777216;       // 32*8*128*128 =  4,194,304
    float* l2 = l3 + 4194304;        // 32*8*64*64   =  1,048,576
    float* r1 = l2 + 1048576;        // 32*64*64     =    131,072  (l1 eliminated)
    float* r2 = r1 + 131072;         // 32*128*128   =    524,288
    float* r3 = r2 + 524288;         // 32*256*256   =  2,097,152

    dim3 blkF(512), blk(256);
    auto nblocks = [](long total) { return dim3((unsigned)((total + 255) / 256)); };

    // ---- forward transform: wave-per-channel ----
    fwd_conv_wave_kernel<<<dim3(32 * 8 * 8), blkF, 0, stream>>>(
        x, 512L * 512, fwd_f, l4, 512, 512, 256, 256, N);
    fwd_conv_wave_kernel<<<dim3(32 * 4 * 4), blkF, 0, stream>>>(
        l4, 8L * 256 * 256, fwd_f, l3, 256, 256, 128, 128, N);
    fwd_conv_wave_kernel<<<dim3(32 * 2 * 2), blkF, 0, stream>>>(
        l3, 8L * 128 * 128, fwd_f, l2, 128, 128, 64, 64, N);

    // ---- fused fwd level 4 + inv level 1 (one block per image) ----
    fwd4_inv1_fused_kernel<<<dim3(32), blkF, 0, stream>>>(l2, fwd_f, inv_f, r1);

    // ---- inverse transform levels 2-4 (pipelined kernel) ----
    inv_tconv_kernel<<<nblocks(32L * 32 * 32), blk, 0, stream>>>(
        r1, 64L * 64, l2, inv_f, r2, 64, 64, N);
    inv_tconv_kernel<<<nblocks(32L * 64 * 64), blk, 0, stream>>>(
        r2, 128L * 128, l3, inv_f, r3, 128, 128, N);
    inv_tconv_kernel<<<nblocks(32L * 128 * 128), blk, 0, stream>>>(
        r3, 256L * 256, l4, inv_f, out, 256, 256, N);
}

// Round 21
// 96.094 us; speedup vs baseline: 2.1163x; 2.1163x over previous
//
#include <hip/hip_runtime.h>

#define NORIENT 8

// XCD-aware block swizzle (bijective when gridDim % 8 == 0; all our grids are).
__device__ __forceinline__ unsigned xcd_swz(unsigned bid, unsigned nwg) {
    unsigned chunk = nwg >> 3;
    return (nwg & 7u) ? bid : (bid & 7u) * chunk + (bid >> 3);
}

// -------- forward, wave-per-channel: stride-2 5x5 conv, 1 -> 8 ch --------
// Wave w computes channel w only -> 25 weights hoisted into SGPRs once;
// the FMA body has zero scalar/global loads. LDS layout col c -> c+4*(c>>3)
// spreads the lane stride across banks. [R12-proven best]
__global__ void fwd_conv_wave_kernel(const float* __restrict__ in, long in_img_stride,
                                     const float* __restrict__ filt,
                                     float* __restrict__ out,
                                     int H, int W, int OH, int OW, int N) {
    constexpr int SROW = 104;
    __shared__ float tile[67 * SROW];      // 27,872 B

    int nbx = OW >> 5, nby = OH >> 5;
    unsigned sb = xcd_swz(blockIdx.x, gridDim.x);
    int bx = (int)(sb % nbx);
    unsigned t = sb / nbx;
    int by = (int)(t % nby);
    int n = (int)(t / nby);

    const float* __restrict__ ip = in + (long)n * in_img_stride;
    int tid = threadIdx.x;

    int w = __builtin_amdgcn_readfirstlane(tid >> 6);
    const float* __restrict__ F = filt + w * 25;
    float Wt[25];
#pragma unroll
    for (int k = 0; k < 25; ++k) Wt[k] = F[k];

    int gy0 = 64 * by - 2, gx0 = 64 * bx - 4;
#pragma unroll
    for (int k = 0; k < 3; ++k) {
        int e = tid + k * 512;
        if (e < 67 * 18) {
            int row = e / 18, m = e - row * 18;
            int gy = gy0 + row, gx = gx0 + 4 * m;
            bool vl = (gy >= 0) & (gy < H) & (gx >= 0) & (gx <= W - 4);
            float4 val = *(const float4*)(ip + (vl ? ((long)gy * W + gx) : 0));
            float msk = vl ? 1.f : 0.f;
            int off = row * SROW + 4 * m + 4 * (m >> 1);
            *(float4*)&tile[off] = make_float4(val.x * msk, val.y * msk,
                                               val.z * msk, val.w * msk);
        }
    }
    __syncthreads();

    int lane = tid & 63;
    int lx = lane & 7, ly = lane >> 3;

    float acc[4][4];
#pragma unroll
    for (int o = 0; o < 4; ++o)
#pragma unroll
        for (int dx = 0; dx < 4; ++dx) acc[o][dx] = 0.f;

#pragma unroll
    for (int r = 0; r < 11; ++r) {
        int base = (8 * ly + r) * SROW + 12 * lx;
        float2 A2 = *(const float2*)&tile[base + 2];
        float4 B  = *(const float4*)&tile[base + 4];
        float4 C  = *(const float4*)&tile[base + 12];
        float  D  = tile[base + 16];
        float Q[11] = {A2.x, A2.y, B.x, B.y, B.z, B.w, C.x, C.y, C.z, C.w, D};

#pragma unroll
        for (int o = 0; o < 4; ++o) {
            int i = r - 2 * o;
            if (i < 0 || i > 4) continue;
#pragma unroll
            for (int j = 0; j < 5; ++j) {
                float wv = Wt[i * 5 + j];
#pragma unroll
                for (int dx = 0; dx < 4; ++dx)
                    acc[o][dx] = fmaf(Q[2 * dx + j], wv, acc[o][dx]);
            }
        }
    }

    long cs = (long)OH * OW;
    int oy = 32 * by + 4 * ly, ox = 32 * bx + 4 * lx;
    long ob = ((long)n * NORIENT + w) * cs + (long)oy * OW + ox;
#pragma unroll
    for (int o = 0; o < 4; ++o)
        *(float4*)(out + ob + (long)o * OW) =
            make_float4(acc[o][0], acc[o][1], acc[o][2], acc[o][3]);
}

// -------- fused fwd level 4 + inv level 1: one block = one image (R18) --------
__global__ void fwd4_inv1_fused_kernel(const float* __restrict__ l2, // [n][8][64][64]
                                       const float* __restrict__ fwd_f,
                                       const float* __restrict__ inv_f,
                                       float* __restrict__ r1) {     // [n][64][64]
    constexpr int SROW = 104;
    __shared__ float tile[67 * SROW];        // 27,872 B
    __shared__ float l1t[NORIENT * 32 * 32]; // 32,768 B

    int n = blockIdx.x;
    const float* __restrict__ ip = l2 + (long)n * 8 * 64 * 64;   // channel 0 plane
    int tid = threadIdx.x;

    int w = __builtin_amdgcn_readfirstlane(tid >> 6);
    {
        const float* __restrict__ F = fwd_f + w * 25;
        float Wt[25];
#pragma unroll
        for (int k = 0; k < 25; ++k) Wt[k] = F[k];

#pragma unroll
        for (int k = 0; k < 3; ++k) {
            int e = tid + k * 512;
            if (e < 67 * 18) {
                int row = e / 18, m = e - row * 18;
                int gy = -2 + row, gx = -4 + 4 * m;
                bool vl = (gy >= 0) & (gy < 64) & (gx >= 0) & (gx <= 60);
                float4 val = *(const float4*)(ip + (vl ? ((long)gy * 64 + gx) : 0));
                float msk = vl ? 1.f : 0.f;
                int off = row * SROW + 4 * m + 4 * (m >> 1);
                *(float4*)&tile[off] = make_float4(val.x * msk, val.y * msk,
                                                   val.z * msk, val.w * msk);
            }
        }
        __syncthreads();

        int lane = tid & 63;
        int lx = lane & 7, ly = lane >> 3;

        float acc[4][4];
#pragma unroll
        for (int o = 0; o < 4; ++o)
#pragma unroll
            for (int dx = 0; dx < 4; ++dx) acc[o][dx] = 0.f;

#pragma unroll
        for (int r = 0; r < 11; ++r) {
            int base = (8 * ly + r) * SROW + 12 * lx;
            float2 A2 = *(const float2*)&tile[base + 2];
            float4 B  = *(const float4*)&tile[base + 4];
            float4 C  = *(const float4*)&tile[base + 12];
            float  D  = tile[base + 16];
            float Q[11] = {A2.x, A2.y, B.x, B.y, B.z, B.w, C.x, C.y, C.z, C.w, D};

#pragma unroll
            for (int o = 0; o < 4; ++o) {
                int i = r - 2 * o;
                if (i < 0 || i > 4) continue;
#pragma unroll
                for (int j = 0; j < 5; ++j) {
                    float wv = Wt[i * 5 + j];
#pragma unroll
                    for (int dx = 0; dx < 4; ++dx)
                        acc[o][dx] = fmaf(Q[2 * dx + j], wv, acc[o][dx]);
                }
            }
        }

#pragma unroll
        for (int o = 0; o < 4; ++o)
            *(float4*)&l1t[w * 1024 + (4 * ly + o) * 32 + 4 * lx] =
                make_float4(acc[o][0], acc[o][1], acc[o][2], acc[o][3]);
    }
    __syncthreads();

    if (tid < 256) {
        int b0 = tid & 15, a0 = tid >> 4;

        bool fmv = a0 > 0, fpv = a0 < 15;
        bool um = b0 > 0, up = b0 < 15;
        float fm = fmv ? 1.f : 0.f, fp_ = fpv ? 1.f : 0.f;
        int r0 = (fmv ? 2 * a0 - 1 : 0) * 32;
        int r1o = (2 * a0) * 32;
        int r2o = (2 * a0 + 1) * 32;
        int r3o = (fpv ? 2 * a0 + 2 : 2 * a0 + 1) * 32;
        int cL = um ? 2 * b0 - 2 : 0;
        int cM = 2 * b0;
        int cR = up ? 2 * b0 + 2 : 0;
        const int ro[4] = {r0, r1o, r2o, r3o};
        const float rm[4] = {fm, 1.f, 1.f, fp_};

        float acc[2][2][2][2];
#pragma unroll
        for (int i = 0; i < 2; ++i)
#pragma unroll
            for (int j = 0; j < 2; ++j)
#pragma unroll
                for (int k = 0; k < 2; ++k)
#pragma unroll
                    for (int l = 0; l < 2; ++l) acc[i][j][k][l] = 0.f;

#pragma unroll
        for (int c = 0; c < NORIENT; ++c) {
            const float* __restrict__ F = inv_f + c * 25;
            int coff = c * 1024;
            float P[4][4];
#pragma unroll
            for (int r = 0; r < 4; ++r) {
                int base = coff + ro[r];
                float2 L = *(const float2*)&l1t[base + cL];
                float2 M = *(const float2*)&l1t[base + cM];
                float2 R = *(const float2*)&l1t[base + cR];
                float mask = rm[r];
                P[r][0] = (um ? L.y : 0.f) * mask;
                P[r][1] = M.x * mask;
                P[r][2] = M.y * mask;
                P[r][3] = (up ? R.x : 0.f) * mask;
            }
#pragma unroll
            for (int a = 0; a < 3; ++a) {
#pragma unroll
                for (int b = 0; b < 3; ++b) {
                    float w00 = F[(4 - 2 * a) * 5 + (4 - 2 * b)];
                    float w01 = (b >= 1) ? F[(4 - 2 * a) * 5 + (5 - 2 * b)] : 0.f;
                    float w10 = (a >= 1) ? F[(5 - 2 * a) * 5 + (4 - 2 * b)] : 0.f;
                    float w11 = (a >= 1 && b >= 1) ? F[(5 - 2 * a) * 5 + (5 - 2 * b)] : 0.f;
#pragma unroll
                    for (int sr = 0; sr < 2; ++sr) {
#pragma unroll
                        for (int sc = 0; sc < 2; ++sc) {
                            float pv = P[sr + a][sc + b];
                            acc[sr][sc][0][0] = fmaf(pv, w00, acc[sr][sc][0][0]);
                            if (b >= 1) acc[sr][sc][0][1] = fmaf(pv, w01, acc[sr][sc][0][1]);
                            if (a >= 1) acc[sr][sc][1][0] = fmaf(pv, w10, acc[sr][sc][1][0]);
                            if (a >= 1 && b >= 1)
                                        acc[sr][sc][1][1] = fmaf(pv, w11, acc[sr][sc][1][1]);
                        }
                    }
                }
            }
        }

        long ob = (long)n * 4096 + (long)(4 * a0) * 64 + 4 * b0;
        *(float4*)(r1 + ob)       = make_float4(acc[0][0][0][0], acc[0][0][0][1],
                                                acc[0][1][0][0], acc[0][1][0][1]);
        *(float4*)(r1 + ob + 64)  = make_float4(acc[0][0][1][0], acc[0][0][1][1],
                                                acc[0][1][1][0], acc[0][1][1][1]);
        *(float4*)(r1 + ob + 128) = make_float4(acc[1][0][0][0], acc[1][0][0][1],
                                                acc[1][1][0][0], acc[1][1][0][1]);
        *(float4*)(r1 + ob + 192) = make_float4(acc[1][0][1][0], acc[1][0][1][1],
                                                acc[1][1][1][0], acc[1][1][1][1]);
    }
}

// -------- inverse direct, merged loads (R19, session-best inverse) --------
// Per patch row: two odd-offset float2 loads (8 VMEM/channel). Edge lanes
// via clamp+select. FMA set identical to the R4-verified kernel.
// R20 lesson: explicit 2-deep channel pipelining (+32 VGPR in-flight state)
// blows the 64-VGPR wall -> 115 MB scratch spill, 2x slower. Compiler's
// implicit schedule at <=64 VGPR is the optimum for this structure.
__global__ void inv_tconv_kernel(const float* __restrict__ rec, long rec_img_stride,
                                 const float* __restrict__ coef,
                                 const float* __restrict__ filt,
                                 float* __restrict__ out,
                                 int h, int w, int N) {
    int h2 = h >> 1, w2 = w >> 1;
    unsigned sb = xcd_swz(blockIdx.x, gridDim.x);
    long idx = (long)sb * blockDim.x + threadIdx.x;
    long total = (long)N * h2 * w2;
    if (idx >= total) return;
    int b0 = (int)(idx % w2);
    long t = idx / w2;
    int a0 = (int)(t % h2);
    int n = (int)(t / h2);

    const float* __restrict__ rp = rec + (long)n * rec_img_stride;
    const float* __restrict__ cp = coef + (long)n * (long)NORIENT * h * w;
    long cs = (long)h * w;

    bool fmv = a0 > 0, fpv = a0 < h2 - 1;
    bool um = b0 > 0, up = b0 < w2 - 1;
    float fm = fmv ? 1.f : 0.f, fp_ = fpv ? 1.f : 0.f;
    int r0 = (fmv ? 2 * a0 - 1 : 0) * w;
    int r1 = (2 * a0) * w;
    int r2 = (2 * a0 + 1) * w;
    int r3 = (fpv ? 2 * a0 + 2 : 2 * a0 + 1) * w;
    int am  = um ? 2 * b0 - 1 : 0;      // float2 covering P0,P1 (or P1 at edge)
    int bm2 = up ? 2 * b0 + 1 : w - 2;  // float2 covering P2,P3 (or P2 at edge)

    float acc[2][2][2][2];  // [sr][sc][dy][dx]
#pragma unroll
    for (int i = 0; i < 2; ++i)
#pragma unroll
        for (int j = 0; j < 2; ++j)
#pragma unroll
            for (int k = 0; k < 2; ++k)
#pragma unroll
                for (int l = 0; l < 2; ++l) acc[i][j][k][l] = 0.f;

    auto do_channel = [&](const float* __restrict__ src, const float* __restrict__ F) {
        float P[4][4];
        const int ro[4] = {r0, r1, r2, r3};
        const float rm[4] = {fm, 1.f, 1.f, fp_};
#pragma unroll
        for (int r = 0; r < 4; ++r) {
            const float* base = src + ro[r];
            float2 X = *(const float2*)(base + am);
            float2 Y = *(const float2*)(base + bm2);
            float mask = rm[r];
            P[r][0] = (um ? X.x : 0.f) * mask;
            P[r][1] = (um ? X.y : X.x) * mask;
            P[r][2] = (up ? Y.x : Y.y) * mask;
            P[r][3] = (up ? Y.y : 0.f) * mask;
        }
#pragma unroll
        for (int a = 0; a < 3; ++a) {
#pragma unroll
            for (int b = 0; b < 3; ++b) {
                float w00 = F[(4 - 2 * a) * 5 + (4 - 2 * b)];
                float w01 = (b >= 1) ? F[(4 - 2 * a) * 5 + (5 - 2 * b)] : 0.f;
                float w10 = (a >= 1) ? F[(5 - 2 * a) * 5 + (4 - 2 * b)] : 0.f;
                float w11 = (a >= 1 && b >= 1) ? F[(5 - 2 * a) * 5 + (5 - 2 * b)] : 0.f;
#pragma unroll
                for (int sr = 0; sr < 2; ++sr) {
#pragma unroll
                    for (int sc = 0; sc < 2; ++sc) {
                        float pv = P[sr + a][sc + b];
                        acc[sr][sc][0][0] = fmaf(pv, w00, acc[sr][sc][0][0]);
                        if (b >= 1) acc[sr][sc][0][1] = fmaf(pv, w01, acc[sr][sc][0][1]);
                        if (a >= 1) acc[sr][sc][1][0] = fmaf(pv, w10, acc[sr][sc][1][0]);
                        if (a >= 1 && b >= 1)
                                    acc[sr][sc][1][1] = fmaf(pv, w11, acc[sr][sc][1][1]);
                    }
                }
            }
        }
    };

    do_channel(rp, filt);
#pragma unroll
    for (int c = 1; c < NORIENT; ++c)
        do_channel(cp + (long)c * cs, filt + c * 25);

    int OW = w << 1;
    long ob = (long)n * 4 * cs + (long)(4 * a0) * OW + 4 * b0;
    *(float4*)(out + ob)          = make_float4(acc[0][0][0][0], acc[0][0][0][1],
                                                acc[0][1][0][0], acc[0][1][0][1]);
    *(float4*)(out + ob + OW)     = make_float4(acc[0][0][1][0], acc[0][0][1][1],
                                                acc[0][1][1][0], acc[0][1][1][1]);
    *(float4*)(out + ob + 2 * OW) = make_float4(acc[1][0][0][0], acc[1][0][0][1],
                                                acc[1][1][0][0], acc[1][1][0][1]);
    *(float4*)(out + ob + 3 * OW) = make_float4(acc[1][0][1][0], acc[1][0][1][1],
                                                acc[1][1][1][0], acc[1][1][1][1]);
}

extern "C" void kernel_launch(void* const* d_in, const int* in_sizes, int n_in,
                              void* d_out, int out_size, void* d_ws, size_t ws_size,
                              hipStream_t stream) {
    const float* x     = (const float*)d_in[0];
    const float* fwd_f = (const float*)d_in[1];
    const float* inv_f = (const float*)d_in[2];
    float* out = (float*)d_out;
    float* ws  = (float*)d_ws;

    const int N = 32;

    // workspace layout (floats) — all offsets multiples of 4 -> 16B aligned
    float* l4 = ws;                  // 32*8*256*256 = 16,777,216
    float* l3 = l4 + 16777216;       // 32*8*128*128 =  4,194,304
    float* l2 = l3 + 4194304;        // 32*8*64*64   =  1,048,576
    float* r1 = l2 + 1048576;        // 32*64*64     =    131,072  (l1 eliminated)
    float* r2 = r1 + 131072;         // 32*128*128   =    524,288
    float* r3 = r2 + 524288;         // 32*256*256   =  2,097,152

    dim3 blkF(512), blk(256);
    auto nblocks = [](long total) { return dim3((unsigned)((total + 255) / 256)); };

    // ---- forward transform: wave-per-channel ----
    fwd_conv_wave_kernel<<<dim3(32 * 8 * 8), blkF, 0, stream>>>(
        x, 512L * 512, fwd_f, l4, 512, 512, 256, 256, N);
    fwd_conv_wave_kernel<<<dim3(32 * 4 * 4), blkF, 0, stream>>>(
        l4, 8L * 256 * 256, fwd_f, l3, 256, 256, 128, 128, N);
    fwd_conv_wave_kernel<<<dim3(32 * 2 * 2), blkF, 0, stream>>>(
        l3, 8L * 128 * 128, fwd_f, l2, 128, 128, 64, 64, N);

    // ---- fused fwd level 4 + inv level 1 (one block per image) ----
    fwd4_inv1_fused_kernel<<<dim3(32), blkF, 0, stream>>>(l2, fwd_f, inv_f, r1);

    // ---- inverse transform levels 2-4 (merged-load kernel) ----
    inv_tconv_kernel<<<nblocks(32L * 32 * 32), blk, 0, stream>>>(
        r1, 64L * 64, l2, inv_f, r2, 64, 64, N);
    inv_tconv_kernel<<<nblocks(32L * 64 * 64), blk, 0, stream>>>(
        r2, 128L * 128, l3, inv_f, r3, 128, 128, N);
    inv_tconv_kernel<<<nblocks(32L * 128 * 128), blk, 0, stream>>>(
        r3, 256L * 256, l4, inv_f, out, 256, 256, N);
}

// Round 22
// 91.130 us; speedup vs baseline: 2.2316x; 1.0545x over previous
//
#include <hip/hip_runtime.h>

#define NORIENT 8

// XCD-aware block swizzle (bijective when gridDim % 8 == 0; all our grids are).
__device__ __forceinline__ unsigned xcd_swz(unsigned bid, unsigned nwg) {
    unsigned chunk = nwg >> 3;
    return (nwg & 7u) ? bid : (bid & 7u) * chunk + (bid >> 3);
}

// -------- forward, wave-per-channel: stride-2 5x5 conv, 1 -> 8 ch (R21 exact) --------
__global__ void fwd_conv_wave_kernel(const float* __restrict__ in, long in_img_stride,
                                     const float* __restrict__ filt,
                                     float* __restrict__ out,
                                     int H, int W, int OH, int OW, int N) {
    constexpr int SROW = 104;
    __shared__ float tile[67 * SROW];      // 27,872 B

    int nbx = OW >> 5, nby = OH >> 5;
    unsigned sb = xcd_swz(blockIdx.x, gridDim.x);
    int bx = (int)(sb % nbx);
    unsigned t = sb / nbx;
    int by = (int)(t % nby);
    int n = (int)(t / nby);

    const float* __restrict__ ip = in + (long)n * in_img_stride;
    int tid = threadIdx.x;

    int w = __builtin_amdgcn_readfirstlane(tid >> 6);
    const float* __restrict__ F = filt + w * 25;
    float Wt[25];
#pragma unroll
    for (int k = 0; k < 25; ++k) Wt[k] = F[k];

    int gy0 = 64 * by - 2, gx0 = 64 * bx - 4;
#pragma unroll
    for (int k = 0; k < 3; ++k) {
        int e = tid + k * 512;
        if (e < 67 * 18) {
            int row = e / 18, m = e - row * 18;
            int gy = gy0 + row, gx = gx0 + 4 * m;
            bool vl = (gy >= 0) & (gy < H) & (gx >= 0) & (gx <= W - 4);
            float4 val = *(const float4*)(ip + (vl ? ((long)gy * W + gx) : 0));
            float msk = vl ? 1.f : 0.f;
            int off = row * SROW + 4 * m + 4 * (m >> 1);
            *(float4*)&tile[off] = make_float4(val.x * msk, val.y * msk,
                                               val.z * msk, val.w * msk);
        }
    }
    __syncthreads();

    int lane = tid & 63;
    int lx = lane & 7, ly = lane >> 3;

    float acc[4][4];
#pragma unroll
    for (int o = 0; o < 4; ++o)
#pragma unroll
        for (int dx = 0; dx < 4; ++dx) acc[o][dx] = 0.f;

#pragma unroll
    for (int r = 0; r < 11; ++r) {
        int base = (8 * ly + r) * SROW + 12 * lx;
        float2 A2 = *(const float2*)&tile[base + 2];
        float4 B  = *(const float4*)&tile[base + 4];
        float4 C  = *(const float4*)&tile[base + 12];
        float  D  = tile[base + 16];
        float Q[11] = {A2.x, A2.y, B.x, B.y, B.z, B.w, C.x, C.y, C.z, C.w, D};

#pragma unroll
        for (int o = 0; o < 4; ++o) {
            int i = r - 2 * o;
            if (i < 0 || i > 4) continue;
#pragma unroll
            for (int j = 0; j < 5; ++j) {
                float wv = Wt[i * 5 + j];
#pragma unroll
                for (int dx = 0; dx < 4; ++dx)
                    acc[o][dx] = fmaf(Q[2 * dx + j], wv, acc[o][dx]);
            }
        }
    }

    long cs = (long)OH * OW;
    int oy = 32 * by + 4 * ly, ox = 32 * bx + 4 * lx;
    long ob = ((long)n * NORIENT + w) * cs + (long)oy * OW + ox;
#pragma unroll
    for (int o = 0; o < 4; ++o)
        *(float4*)(out + ob + (long)o * OW) =
            make_float4(acc[o][0], acc[o][1], acc[o][2], acc[o][3]);
}

// -------- fused fwd level 4 + inv level 1: one block = one image (R21 exact) --------
__global__ void fwd4_inv1_fused_kernel(const float* __restrict__ l2, // [n][8][64][64]
                                       const float* __restrict__ fwd_f,
                                       const float* __restrict__ inv_f,
                                       float* __restrict__ r1) {     // [n][64][64]
    constexpr int SROW = 104;
    __shared__ float tile[67 * SROW];        // 27,872 B
    __shared__ float l1t[NORIENT * 32 * 32]; // 32,768 B

    int n = blockIdx.x;
    const float* __restrict__ ip = l2 + (long)n * 8 * 64 * 64;   // channel 0 plane
    int tid = threadIdx.x;

    int w = __builtin_amdgcn_readfirstlane(tid >> 6);
    {
        const float* __restrict__ F = fwd_f + w * 25;
        float Wt[25];
#pragma unroll
        for (int k = 0; k < 25; ++k) Wt[k] = F[k];

#pragma unroll
        for (int k = 0; k < 3; ++k) {
            int e = tid + k * 512;
            if (e < 67 * 18) {
                int row = e / 18, m = e - row * 18;
                int gy = -2 + row, gx = -4 + 4 * m;
                bool vl = (gy >= 0) & (gy < 64) & (gx >= 0) & (gx <= 60);
                float4 val = *(const float4*)(ip + (vl ? ((long)gy * 64 + gx) : 0));
                float msk = vl ? 1.f : 0.f;
                int off = row * SROW + 4 * m + 4 * (m >> 1);
                *(float4*)&tile[off] = make_float4(val.x * msk, val.y * msk,
                                                   val.z * msk, val.w * msk);
            }
        }
        __syncthreads();

        int lane = tid & 63;
        int lx = lane & 7, ly = lane >> 3;

        float acc[4][4];
#pragma unroll
        for (int o = 0; o < 4; ++o)
#pragma unroll
            for (int dx = 0; dx < 4; ++dx) acc[o][dx] = 0.f;

#pragma unroll
        for (int r = 0; r < 11; ++r) {
            int base = (8 * ly + r) * SROW + 12 * lx;
            float2 A2 = *(const float2*)&tile[base + 2];
            float4 B  = *(const float4*)&tile[base + 4];
            float4 C  = *(const float4*)&tile[base + 12];
            float  D  = tile[base + 16];
            float Q[11] = {A2.x, A2.y, B.x, B.y, B.z, B.w, C.x, C.y, C.z, C.w, D};

#pragma unroll
            for (int o = 0; o < 4; ++o) {
                int i = r - 2 * o;
                if (i < 0 || i > 4) continue;
#pragma unroll
                for (int j = 0; j < 5; ++j) {
                    float wv = Wt[i * 5 + j];
#pragma unroll
                    for (int dx = 0; dx < 4; ++dx)
                        acc[o][dx] = fmaf(Q[2 * dx + j], wv, acc[o][dx]);
                }
            }
        }

#pragma unroll
        for (int o = 0; o < 4; ++o)
            *(float4*)&l1t[w * 1024 + (4 * ly + o) * 32 + 4 * lx] =
                make_float4(acc[o][0], acc[o][1], acc[o][2], acc[o][3]);
    }
    __syncthreads();

    if (tid < 256) {
        int b0 = tid & 15, a0 = tid >> 4;

        bool fmv = a0 > 0, fpv = a0 < 15;
        bool um = b0 > 0, up = b0 < 15;
        float fm = fmv ? 1.f : 0.f, fp_ = fpv ? 1.f : 0.f;
        int r0 = (fmv ? 2 * a0 - 1 : 0) * 32;
        int r1o = (2 * a0) * 32;
        int r2o = (2 * a0 + 1) * 32;
        int r3o = (fpv ? 2 * a0 + 2 : 2 * a0 + 1) * 32;
        int cL = um ? 2 * b0 - 2 : 0;
        int cM = 2 * b0;
        int cR = up ? 2 * b0 + 2 : 0;
        const int ro[4] = {r0, r1o, r2o, r3o};
        const float rm[4] = {fm, 1.f, 1.f, fp_};

        float acc[2][2][2][2];
#pragma unroll
        for (int i = 0; i < 2; ++i)
#pragma unroll
            for (int j = 0; j < 2; ++j)
#pragma unroll
                for (int k = 0; k < 2; ++k)
#pragma unroll
                    for (int l = 0; l < 2; ++l) acc[i][j][k][l] = 0.f;

#pragma unroll
        for (int c = 0; c < NORIENT; ++c) {
            const float* __restrict__ F = inv_f + c * 25;
            int coff = c * 1024;
            float P[4][4];
#pragma unroll
            for (int r = 0; r < 4; ++r) {
                int base = coff + ro[r];
                float2 L = *(const float2*)&l1t[base + cL];
                float2 M = *(const float2*)&l1t[base + cM];
                float2 R = *(const float2*)&l1t[base + cR];
                float mask = rm[r];
                P[r][0] = (um ? L.y : 0.f) * mask;
                P[r][1] = M.x * mask;
                P[r][2] = M.y * mask;
                P[r][3] = (up ? R.x : 0.f) * mask;
            }
#pragma unroll
            for (int a = 0; a < 3; ++a) {
#pragma unroll
                for (int b = 0; b < 3; ++b) {
                    float w00 = F[(4 - 2 * a) * 5 + (4 - 2 * b)];
                    float w01 = (b >= 1) ? F[(4 - 2 * a) * 5 + (5 - 2 * b)] : 0.f;
                    float w10 = (a >= 1) ? F[(5 - 2 * a) * 5 + (4 - 2 * b)] : 0.f;
                    float w11 = (a >= 1 && b >= 1) ? F[(5 - 2 * a) * 5 + (5 - 2 * b)] : 0.f;
#pragma unroll
                    for (int sr = 0; sr < 2; ++sr) {
#pragma unroll
                        for (int sc = 0; sc < 2; ++sc) {
                            float pv = P[sr + a][sc + b];
                            acc[sr][sc][0][0] = fmaf(pv, w00, acc[sr][sc][0][0]);
                            if (b >= 1) acc[sr][sc][0][1] = fmaf(pv, w01, acc[sr][sc][0][1]);
                            if (a >= 1) acc[sr][sc][1][0] = fmaf(pv, w10, acc[sr][sc][1][0]);
                            if (a >= 1 && b >= 1)
                                        acc[sr][sc][1][1] = fmaf(pv, w11, acc[sr][sc][1][1]);
                        }
                    }
                }
            }
        }

        long ob = (long)n * 4096 + (long)(4 * a0) * 64 + 4 * b0;
        *(float4*)(r1 + ob)       = make_float4(acc[0][0][0][0], acc[0][0][0][1],
                                                acc[0][1][0][0], acc[0][1][0][1]);
        *(float4*)(r1 + ob + 64)  = make_float4(acc[0][0][1][0], acc[0][0][1][1],
                                                acc[0][1][1][0], acc[0][1][1][1]);
        *(float4*)(r1 + ob + 128) = make_float4(acc[1][0][0][0], acc[1][0][0][1],
                                                acc[1][1][0][0], acc[1][1][0][1]);
        *(float4*)(r1 + ob + 192) = make_float4(acc[1][0][1][0], acc[1][0][1][1],
                                                acc[1][1][1][0], acc[1][1][1][1]);
    }
}

// -------- inverse (DMA-staged): tconv 8 -> 1 ch, stride 2, levels 2-4 --------
// R22: stage the 8ch x 18 x 40 coefficient tile (23 KB + pad) via
// __builtin_amdgcn_global_load_lds width=16 — in-flight state lives in the
// vmcnt queue, NOT VGPRs (the wall that killed R9/R14/R15/R20 prefetch).
// 24 DMA instructions per block (6 per wave), one drain at the barrier.
// Compute = R14's verified site mapping, but 3x float2 LDS reads per row
// (8B-aligned; lane->bank = (2sx+8sy)%32 = exact 2-way = free) and masks
// applied at compute time (equivalent to R14's stage-time zeroing).
__global__ void inv_tconv_dma_kernel(const float* __restrict__ rec, long rec_img_stride,
                                     const float* __restrict__ coef,
                                     const float* __restrict__ filt,
                                     float* __restrict__ out,
                                     int h, int w, int N) {
    constexpr int SROW = 40;            // staged cols (floats)
    constexpr int CH = 18 * SROW;       // 720 floats per channel
    __shared__ float stage[6144];       // 24,576 B (5760 used + DMA pad)

    int nbx = w >> 5, nby = h >> 4;     // site tiles: 16 rows x 32 cols
    unsigned sb = xcd_swz(blockIdx.x, gridDim.x);
    int bx = (int)(sb % nbx);
    unsigned tt = sb / nbx;
    int by = (int)(tt % nby);
    int n = (int)(tt / nby);

    int S0 = 16 * by, Q0 = 32 * bx;     // first site row/col of tile
    long cs = (long)h * w;
    const float* __restrict__ rp = rec + (long)n * rec_img_stride;
    const float* __restrict__ cp = coef + (long)n * NORIENT * cs;

    int tid = threadIdx.x;
    int lane = tid & 63;
    int wv = tid >> 6;                  // wave 0..3

    // ---- DMA stage: float4 slot f -> stage[f*4..f*4+3]; 1440 real + pad ----
    // slot f: ch = f/180, row = (f%180)/10, m = (f%180)%10
    //   staged col 4m  <-> global col Q0-4+4m ; staged row <-> site row S0-1+row
#pragma unroll
    for (int k = 0; k < 6; ++k) {
        int fb = (wv * 6 + k) * 64;     // wave-uniform slot base
        int f = fb + lane;
        int fc = (f < 1440) ? f : 1439; // pad lanes duplicate a safe address
        int ch = fc / 180;
        int rem = fc - ch * 180;
        int row = rem / 10, m = rem - row * 10;
        int gy = S0 - 1 + row;
        gy = gy < 0 ? 0 : (gy >= h ? h - 1 : gy);
        int gx = Q0 - 4 + 4 * m;
        gx = gx < 0 ? 0 : (gx > w - 4 ? w - 4 : gx);
        const float* __restrict__ src = ch ? (cp + (long)ch * cs) : rp;
        __builtin_amdgcn_global_load_lds(src + (long)gy * w + gx,
                                         &stage[(unsigned)f * 4], 16, 0, 0);
    }
    __syncthreads();   // drains vmcnt before any wave reads the tile

    // ---- compute: thread (sx,sy) -> sites (S0+sy, Q0+2sx) and (.., +1) ----
    int sx = tid & 15, sy = tid >> 4;

    // masks (replicate stage-time zeroing semantics at compute time)
    float rm0 = (S0 + sy - 1 >= 0) ? 1.f : 0.f;
    float rm2 = (S0 + sy + 1 < h) ? 1.f : 0.f;
    float cm0 = (Q0 + 2 * sx - 1 >= 0) ? 1.f : 0.f;
    float cm3 = (Q0 + 2 * sx + 2 < w) ? 1.f : 0.f;

    float acc[2][2][2];  // [sc][dy][dx]
#pragma unroll
    for (int i = 0; i < 2; ++i)
#pragma unroll
        for (int j = 0; j < 2; ++j) {
            acc[i][j][0] = 0.f;
            acc[i][j][1] = 0.f;
        }

#pragma unroll
    for (int c = 0; c < NORIENT; ++c) {
        const float* __restrict__ F = filt + c * 25;   // contiguous -> merged s_loads
        const float* __restrict__ tc = &stage[c * CH];

        // patch rows: site rows S0+sy-1..+1 -> LDS rows sy..sy+2
        // patch cols: site cols Q0+2sx-1..+2 -> staged cols 2sx+3..2sx+6
        float P[3][4];
#pragma unroll
        for (int r = 0; r < 3; ++r) {
            const float* rowp = tc + (sy + r) * SROW;
            float2 L  = *(const float2*)(rowp + 2 * sx + 2);   // .y = col 2sx+3
            float2 Fa = *(const float2*)(rowp + 2 * sx + 4);   // cols +4,+5
            float2 Fb = *(const float2*)(rowp + 2 * sx + 6);   // cols +6,+7
            float rmask = (r == 0) ? rm0 : ((r == 2) ? rm2 : 1.f);
            P[r][0] = L.y  * rmask * cm0;
            P[r][1] = Fa.x * rmask;
            P[r][2] = Fa.y * rmask;
            P[r][3] = Fb.x * rmask * cm3;
        }

#pragma unroll
        for (int a = 0; a < 3; ++a) {
#pragma unroll
            for (int b = 0; b < 3; ++b) {
                float w00 = F[(4 - 2 * a) * 5 + (4 - 2 * b)];
                float w01 = (b >= 1) ? F[(4 - 2 * a) * 5 + (5 - 2 * b)] : 0.f;
                float w10 = (a >= 1) ? F[(5 - 2 * a) * 5 + (4 - 2 * b)] : 0.f;
                float w11 = (a >= 1 && b >= 1) ? F[(5 - 2 * a) * 5 + (5 - 2 * b)] : 0.f;
#pragma unroll
                for (int sc = 0; sc < 2; ++sc) {
                    float pv = P[a][sc + b];
                    acc[sc][0][0] = fmaf(pv, w00, acc[sc][0][0]);
                    if (b >= 1) acc[sc][0][1] = fmaf(pv, w01, acc[sc][0][1]);
                    if (a >= 1) acc[sc][1][0] = fmaf(pv, w10, acc[sc][1][0]);
                    if (a >= 1 && b >= 1)
                                acc[sc][1][1] = fmaf(pv, w11, acc[sc][1][1]);
                }
            }
        }
    }

    int OW = w << 1;
    long ob = (long)n * 4 * cs + (long)(2 * (S0 + sy)) * OW + (2 * Q0 + 4 * sx);
    *(float4*)(out + ob)      = make_float4(acc[0][0][0], acc[0][0][1],
                                            acc[1][0][0], acc[1][0][1]);
    *(float4*)(out + ob + OW) = make_float4(acc[0][1][0], acc[0][1][1],
                                            acc[1][1][0], acc[1][1][1]);
}

extern "C" void kernel_launch(void* const* d_in, const int* in_sizes, int n_in,
                              void* d_out, int out_size, void* d_ws, size_t ws_size,
                              hipStream_t stream) {
    const float* x     = (const float*)d_in[0];
    const float* fwd_f = (const float*)d_in[1];
    const float* inv_f = (const float*)d_in[2];
    float* out = (float*)d_out;
    float* ws  = (float*)d_ws;

    const int N = 32;

    // workspace layout (floats) — all offsets multiples of 4 -> 16B aligned
    float* l4 = ws;                  // 32*8*256*256 = 16,777,216
    float* l3 = l4 + 16777216;       // 32*8*128*128 =  4,194,304
    float* l2 = l3 + 4194304;        // 32*8*64*64   =  1,048,576
    float* r1 = l2 + 1048576;        // 32*64*64     =    131,072  (l1 eliminated)
    float* r2 = r1 + 131072;         // 32*128*128   =    524,288
    float* r3 = r2 + 524288;         // 32*256*256   =  2,097,152

    dim3 blkF(512), blk(256);

    // ---- forward transform: wave-per-channel ----
    fwd_conv_wave_kernel<<<dim3(32 * 8 * 8), blkF, 0, stream>>>(
        x, 512L * 512, fwd_f, l4, 512, 512, 256, 256, N);
    fwd_conv_wave_kernel<<<dim3(32 * 4 * 4), blkF, 0, stream>>>(
        l4, 8L * 256 * 256, fwd_f, l3, 256, 256, 128, 128, N);
    fwd_conv_wave_kernel<<<dim3(32 * 2 * 2), blkF, 0, stream>>>(
        l3, 8L * 128 * 128, fwd_f, l2, 128, 128, 64, 64, N);

    // ---- fused fwd level 4 + inv level 1 (one block per image) ----
    fwd4_inv1_fused_kernel<<<dim3(32), blkF, 0, stream>>>(l2, fwd_f, inv_f, r1);

    // ---- inverse transform levels 2-4: DMA-staged (grid = N * h/16 * w/32) ----
    inv_tconv_dma_kernel<<<dim3(32 * 4 * 2), blk, 0, stream>>>(
        r1, 64L * 64, l2, inv_f, r2, 64, 64, N);
    inv_tconv_dma_kernel<<<dim3(32 * 8 * 4), blk, 0, stream>>>(
        r2, 128L * 128, l3, inv_f, r3, 128, 128, N);
    inv_tconv_dma_kernel<<<dim3(32 * 16 * 8), blk, 0, stream>>>(
        r3, 256L * 256, l4, inv_f, out, 256, 256, N);
}